// Round 10
// baseline (242.043 us; speedup 1.0000x reference)
//
#include <hip/hip_runtime.h>

// KAN layer forward, MI355X. Inputs AND outputs are float32 buffers.
// Outputs (flat concat, f32): y_out[1024,128], preacts[1024,128,128],
// postacts[1024,128,128], postspline[1024,128,128].
//
// R13 -> R14: ONE-STREAM-AT-A-TIME writes. All ten prior versions (incl.
// R13's fill-shaped kernel) interleaved stores to three 64MB-apart output
// streams inside every iteration; the 6.6TB/s fill writes ONE monotone
// stream. That interleave is the last never-varied axis (TCC write-combine
// / DRAM row / L3 victim behavior). Now four launches via d_ws (guarded,
// verified-R12 fallback):
//   kan_basis -> ws;  kan_pre: broadcast x -> out_pre (pure single-stream);
//   kan_spl: dot -> out_spl only;  kan_act: recompute dot (VALU ~free),
//   y -> out_act only + y_out butterfly. Same arithmetic/order everywhere
//   -> absmax unchanged. Each phase = one 64MB store region device-wide.
// Predict: kernel ~95 -> ~45-60us, dur 219 -> ~165-185. If neutral: floor
// declaration (all nameable kernel axes falsified).

#define IN_DIM  128
#define OUT_DIM 128
#define NUMG    5
#define KORD    3
#define NB      8          // NUMG + KORD basis functions
#define SIZE    (IN_DIM * OUT_DIM)
#define BATCH   1024
#define G       8          // (fallback kernel) batch rows per block
#define JB      8          // j per block
#define NBG     (BATCH / G)
#define NJO     (OUT_DIM / JB)
#define WSROW   (10 * IN_DIM)              // floats per b in ws
#define RCHUNK  16                         // rows per streamer block

// ---------- basis math (verified R10-R13) ----------
__device__ __forceinline__ void basis_row(const float* __restrict__ grid,
                                          int i, float xv, float* __restrict__ B,
                                          float& silu)
{
    float gr[NUMG + 1];
    #pragma unroll
    for (int rr = 0; rr <= NUMG; ++rr) gr[rr] = grid[i * (NUMG + 1) + rr];

    const float h = (gr[NUMG] - gr[0]) * (1.0f / NUMG);
    float t[NUMG + 1 + 2 * KORD];             // 12 knots
    t[2] = gr[0] - h; t[1] = t[2] - h; t[0] = t[1] - h;
    #pragma unroll
    for (int rr = 0; rr <= NUMG; ++rr) t[KORD + rr] = gr[rr];
    t[9] = gr[NUMG] + h; t[10] = t[9] + h; t[11] = t[10] + h;

    float rcp1[11], rcp2[10], rcp3[9];
    #pragma unroll
    for (int m = 0; m < 11; ++m) rcp1[m] = 1.0f / (t[m + 1] - t[m]);
    #pragma unroll
    for (int m = 0; m < 10; ++m) rcp2[m] = 1.0f / (t[m + 2] - t[m]);
    #pragma unroll
    for (int m = 0; m < 9;  ++m) rcp3[m] = 1.0f / (t[m + 3] - t[m]);

    float Bt[NUMG + 2 * KORD];                // 11 -> 10 -> 9 -> 8
    #pragma unroll
    for (int m = 0; m < NUMG + 2 * KORD; ++m)
        Bt[m] = (xv >= t[m] && xv < t[m + 1]) ? 1.0f : 0.0f;
    #pragma unroll
    for (int m = 0; m < 10; ++m)
        Bt[m] = (xv - t[m]) * rcp1[m] * Bt[m]
              + (t[m + 2] - xv) * rcp1[m + 1] * Bt[m + 1];
    #pragma unroll
    for (int m = 0; m < 9; ++m)
        Bt[m] = (xv - t[m]) * rcp2[m] * Bt[m]
              + (t[m + 3] - xv) * rcp2[m + 1] * Bt[m + 1];
    #pragma unroll
    for (int m = 0; m < 8; ++m)
        Bt[m] = (xv - t[m]) * rcp3[m] * Bt[m]
              + (t[m + 4] - xv) * rcp3[m + 1] * Bt[m + 1];

    #pragma unroll
    for (int m = 0; m < NB; ++m) B[m] = Bt[m];
    silu = xv / (1.0f + __expf(-xv));
}

// ---------- kernel 1: basis producer (512 blocks x 256) ----------
__global__ __launch_bounds__(256) void kan_basis(
    const float* __restrict__ x,
    const float* __restrict__ grid,
    float* __restrict__ ws)
{
    const int idx = blockIdx.x * 256 + threadIdx.x;
    const int b = idx >> 7;
    const int i = idx & 127;
    const float xv = x[b * IN_DIM + i];

    float B[NB], silu;
    basis_row(grid, i, xv, B, silu);

    float* wp = ws + (size_t)b * WSROW;
    #pragma unroll
    for (int m = 0; m < NB; ++m) wp[m * IN_DIM + i] = B[m];
    wp[8 * IN_DIM + i] = silu;
    wp[9 * IN_DIM + i] = xv;
}

// ---------- kernel 2: out_pre broadcast, ONE monotone stream ----------
// block = batch row b; 256 threads sweep the row's 64KB in address order.
__global__ __launch_bounds__(256) void kan_pre(
    const float* __restrict__ x,
    float* __restrict__ out_pre)
{
    const int b = blockIdx.x;
    const float4* xr = (const float4*)(x + (size_t)b * IN_DIM); // 32 float4
    float4* op = (float4*)(out_pre + (size_t)b * SIZE);         // 4096 float4
    #pragma unroll
    for (int k = 0; k < 16; ++k) {
        const int p = k * 256 + threadIdx.x;
        op[p] = xr[p & 31];            // preacts[b][j][i] = x[b][i]
    }
}

// ---------- shared phase-2 lane setup ----------
#define STREAM_PROLOG                                                     \
    const int tid  = threadIdx.x;                                         \
    const int lane = tid & 63;                                            \
    const int w    = tid >> 6;                                            \
    const int il   = lane & 31;                                           \
    const int jh   = lane >> 5;                                           \
    const int i4   = il << 2;                                             \
    const int jo = blockIdx.x & (NJO - 1);                                \
    const int bc = blockIdx.x >> 4;                                       \
    const int j  = jo * JB + w * 2 + jh;                                  \
    float4 cfq[8];                                                        \
    {                                                                     \
        const float4* cp = (const float4*)coef;                           \
        _Pragma("unroll")                                                 \
        for (int q = 0; q < 8; ++q)                                       \
            cfq[q] = cp[(size_t)j * 256 + il * 8 + q];                    \
    }                                                                     \
    const int sS = j * IN_DIM + i4;                                       \
    float cfs[4][NB];                                                     \
    _Pragma("unroll")                                                     \
    for (int k = 0; k < 4; ++k) {                                         \
        const float4 lo = cfq[2 * k], hi = cfq[2 * k + 1];                \
        cfs[k][0] = lo.x; cfs[k][1] = lo.y;                               \
        cfs[k][2] = lo.z; cfs[k][3] = lo.w;                               \
        cfs[k][4] = hi.x; cfs[k][5] = hi.y;                               \
        cfs[k][6] = hi.z; cfs[k][7] = hi.w;                               \
    }

#define DOT4(bas, sp0, sp1, sp2, sp3)                                     \
    float sp0 = cfs[0][0] * bas[0].x;                                     \
    float sp1 = cfs[1][0] * bas[0].y;                                     \
    float sp2 = cfs[2][0] * bas[0].z;                                     \
    float sp3 = cfs[3][0] * bas[0].w;                                     \
    _Pragma("unroll")                                                     \
    for (int m = 1; m < NB; ++m) {                                        \
        const float4 b4 = bas[m];                                         \
        sp0 = fmaf(cfs[0][m], b4.x, sp0);                                 \
        sp1 = fmaf(cfs[1][m], b4.y, sp1);                                 \
        sp2 = fmaf(cfs[2][m], b4.z, sp2);                                 \
        sp3 = fmaf(cfs[3][m], b4.w, sp3);                                 \
    }

// ---------- kernel 3: out_spl only (single store stream) ----------
__global__ __launch_bounds__(256) void kan_spl(
    const float* __restrict__ ws,
    const float* __restrict__ coef,
    float* __restrict__ out_spl)
{
    STREAM_PROLOG

    #pragma unroll
    for (int r = 0; r < RCHUNK; ++r) {
        const int b_r = bc * RCHUNK + r;
        const float* wp = ws + (size_t)b_r * WSROW;

        float4 bas[NB];
        #pragma unroll
        for (int m = 0; m < NB; ++m)
            bas[m] = *(const float4*)&wp[m * IN_DIM + i4];

        DOT4(bas, sp0, sp1, sp2, sp3)

        const size_t e = (size_t)b_r * SIZE + (size_t)sS;
        *(float4*)&out_spl[e] = make_float4(sp0, sp1, sp2, sp3);
    }
}

// ---------- kernel 4: out_act + y_out (single big store stream) ----------
__global__ __launch_bounds__(256) void kan_act(
    const float* __restrict__ ws,
    const float* __restrict__ coef,
    const float* __restrict__ scale_base,
    const float* __restrict__ scale_sp,
    const float* __restrict__ mask,
    float* __restrict__ out_y,
    float* __restrict__ out_act)
{
    STREAM_PROLOG

    const float4 mkv = *(const float4*)&mask[sS];
    const float4 sbv = *(const float4*)&scale_base[sS];
    const float4 ssv = *(const float4*)&scale_sp[sS];
    const float mkA[4] = {mkv.x, mkv.y, mkv.z, mkv.w};
    const float sbA[4] = {sbv.x, sbv.y, sbv.z, sbv.w};
    const float ssA[4] = {ssv.x, ssv.y, ssv.z, ssv.w};

    float py[RCHUNK];

    #pragma unroll
    for (int r = 0; r < RCHUNK; ++r) {
        const int b_r = bc * RCHUNK + r;
        const float* wp = ws + (size_t)b_r * WSROW;

        float4 bas[NB];
        #pragma unroll
        for (int m = 0; m < NB; ++m)
            bas[m] = *(const float4*)&wp[m * IN_DIM + i4];
        const float4 slv = *(const float4*)&wp[8 * IN_DIM + i4];

        DOT4(bas, sp0, sp1, sp2, sp3)

        const float spA[4] = {sp0, sp1, sp2, sp3};
        const float slA[4] = {slv.x, slv.y, slv.z, slv.w};
        float y[4];
        #pragma unroll
        for (int k = 0; k < 4; ++k)
            y[k] = mkA[k] * (sbA[k] * slA[k] + ssA[k] * spA[k]);

        const size_t e = (size_t)b_r * SIZE + (size_t)sS;
        *(float4*)&out_act[e] = make_float4(y[0], y[1], y[2], y[3]);

        py[r] = (y[0] + y[1]) + (y[2] + y[3]);
    }

    #pragma unroll
    for (int off = 16; off > 0; off >>= 1) {
        #pragma unroll
        for (int r = 0; r < RCHUNK; ++r)
            py[r] += __shfl_down(py[r], off, 32);
    }
    if (il == 0) {
        #pragma unroll
        for (int r = 0; r < RCHUNK; ++r)
            out_y[(bc * RCHUNK + r) * OUT_DIM + j] = py[r];
    }
}

// ---------- fallback: verified R12 single-kernel ----------
__global__ __launch_bounds__(256) void kan_fused(
    const float* __restrict__ x,
    const float* __restrict__ grid,
    const float* __restrict__ coef,
    const float* __restrict__ scale_base,
    const float* __restrict__ scale_sp,
    const float* __restrict__ mask,
    float* __restrict__ out)
{
    __shared__ float sBT[G][NB][IN_DIM];
    __shared__ float sSilu[G][IN_DIM];
    __shared__ float sXv[G][IN_DIM];

    const int tid = threadIdx.x;
    const int bg  = blockIdx.x >> 4;
    const int jo  = blockIdx.x & (NJO - 1);

    const int lane = tid & 63;
    const int w    = tid >> 6;
    const int il   = lane & 31;
    const int jh   = lane >> 5;
    const int i4   = il << 2;
    const int j    = jo * JB + w * 2 + jh;

    float4 cfq[8];
    {
        const float4* cp = (const float4*)coef;
        #pragma unroll
        for (int q = 0; q < 8; ++q)
            cfq[q] = cp[(size_t)j * 256 + il * 8 + q];
    }
    const int sS = j * IN_DIM + i4;
    const float4 mkv = *(const float4*)&mask[sS];
    const float4 sbv = *(const float4*)&scale_base[sS];
    const float4 ssv = *(const float4*)&scale_sp[sS];

    {
        const int i  = tid & 127;
        const int r0 = tid >> 7;
        #pragma unroll
        for (int it = 0; it < 4; ++it) {
            const int r = it * 2 + r0;
            const float xv = x[(bg * G + r) * IN_DIM + i];
            float B[NB], silu;
            basis_row(grid, i, xv, B, silu);
            #pragma unroll
            for (int m = 0; m < NB; ++m) sBT[r][m][i] = B[m];
            sSilu[r][i] = silu;
            sXv[r][i]   = xv;
        }
    }
    __syncthreads();

    float cfs[4][NB];
    #pragma unroll
    for (int k = 0; k < 4; ++k) {
        const float4 lo = cfq[2 * k], hi = cfq[2 * k + 1];
        cfs[k][0] = lo.x; cfs[k][1] = lo.y; cfs[k][2] = lo.z; cfs[k][3] = lo.w;
        cfs[k][4] = hi.x; cfs[k][5] = hi.y; cfs[k][6] = hi.z; cfs[k][7] = hi.w;
    }
    const float mkA[4] = {mkv.x, mkv.y, mkv.z, mkv.w};
    const float sbA[4] = {sbv.x, sbv.y, sbv.z, sbv.w};
    const float ssA[4] = {ssv.x, ssv.y, ssv.z, ssv.w};

    float* out_y   = out;
    float* out_pre = out + BATCH * OUT_DIM;
    float* out_act = out_pre + (size_t)BATCH * SIZE;
    float* out_spl = out_act + (size_t)BATCH * SIZE;

    float py[G];
    #pragma unroll
    for (int r = 0; r < G; ++r) {
        float4 bas[NB];
        #pragma unroll
        for (int m = 0; m < NB; ++m)
            bas[m] = *(const float4*)&sBT[r][m][i4];

        float sp0 = cfs[0][0] * bas[0].x;
        float sp1 = cfs[1][0] * bas[0].y;
        float sp2 = cfs[2][0] * bas[0].z;
        float sp3 = cfs[3][0] * bas[0].w;
        #pragma unroll
        for (int m = 1; m < NB; ++m) {
            const float4 b4 = bas[m];
            sp0 = fmaf(cfs[0][m], b4.x, sp0);
            sp1 = fmaf(cfs[1][m], b4.y, sp1);
            sp2 = fmaf(cfs[2][m], b4.z, sp2);
            sp3 = fmaf(cfs[3][m], b4.w, sp3);
        }

        const float4 slv = *(const float4*)&sSilu[r][i4];
        const float4 pxv = *(const float4*)&sXv[r][i4];
        const float spA[4] = {sp0, sp1, sp2, sp3};
        const float slA[4] = {slv.x, slv.y, slv.z, slv.w};
        float y[4];
        #pragma unroll
        for (int k = 0; k < 4; ++k)
            y[k] = mkA[k] * (sbA[k] * slA[k] + ssA[k] * spA[k]);

        const int b_r = bg * G + r;
        const size_t e = (size_t)b_r * SIZE + (size_t)sS;
        *(float4*)&out_pre[e] = pxv;
        *(float4*)&out_act[e] = make_float4(y[0], y[1], y[2], y[3]);
        *(float4*)&out_spl[e] = make_float4(spA[0], spA[1], spA[2], spA[3]);

        py[r] = (y[0] + y[1]) + (y[2] + y[3]);
    }

    #pragma unroll
    for (int off = 16; off > 0; off >>= 1) {
        #pragma unroll
        for (int r = 0; r < G; ++r)
            py[r] += __shfl_down(py[r], off, 32);
    }
    if (il == 0) {
        #pragma unroll
        for (int r = 0; r < G; ++r)
            out_y[(bg * G + r) * OUT_DIM + j] = py[r];
    }
}

extern "C" void kernel_launch(void* const* d_in, const int* in_sizes, int n_in,
                              void* d_out, int out_size, void* d_ws, size_t ws_size,
                              hipStream_t stream)
{
    const size_t WS_NEED = (size_t)BATCH * WSROW * sizeof(float); // 5.25 MB
    float* out_y   = (float*)d_out;
    float* out_pre = out_y + BATCH * OUT_DIM;
    float* out_act = out_pre + (size_t)BATCH * SIZE;
    float* out_spl = out_act + (size_t)BATCH * SIZE;

    if (d_ws != nullptr && ws_size >= WS_NEED) {
        hipLaunchKernelGGL(kan_basis, dim3(BATCH * IN_DIM / 256), dim3(256), 0,
                           stream,
                           (const float*)d_in[0], (const float*)d_in[1],
                           (float*)d_ws);
        hipLaunchKernelGGL(kan_pre, dim3(BATCH), dim3(256), 0, stream,
                           (const float*)d_in[0], out_pre);
        hipLaunchKernelGGL(kan_spl, dim3((BATCH / RCHUNK) * NJO), dim3(256), 0,
                           stream,
                           (const float*)d_ws, (const float*)d_in[2], out_spl);
        hipLaunchKernelGGL(kan_act, dim3((BATCH / RCHUNK) * NJO), dim3(256), 0,
                           stream,
                           (const float*)d_ws, (const float*)d_in[2],
                           (const float*)d_in[3], (const float*)d_in[4],
                           (const float*)d_in[5], out_y, out_act);
    } else {
        hipLaunchKernelGGL(kan_fused, dim3(NJO * NBG), dim3(256), 0, stream,
                           (const float*)d_in[0], (const float*)d_in[1],
                           (const float*)d_in[2], (const float*)d_in[3],
                           (const float*)d_in[4], (const float*)d_in[5],
                           (float*)d_out);
    }
}

// Round 11
// 209.732 us; speedup vs baseline: 1.1541x; 1.1541x over previous
//
#include <hip/hip_runtime.h>

// KAN layer forward, MI355X. Inputs AND outputs are float32 buffers.
// Outputs (flat concat, f32): y_out[1024,128], preacts[1024,128,128],
// postacts[1024,128,128], postspline[1024,128,128].
//
// R15 = R12 restored (empirical best, 210.1 us). R13/R14 falsified the
// last two structural theories (execution shape, store-stream separation)
// and R14 regressed (+32 us: extra launches + duplicate dot + ws re-reads).
// Session conclusion encoded here:
//   dur ~= 121 us harness poison fill (770 MB @ 6.5 TB/s, at the achievable
//   HBM ceiling, immovable) + ~88 us kernel. The kernel is invariant under
//   11 orthogonal interventions (store width/pattern, nt, volume, DS chains
//   [-15 us, only hit], scratch, hoisting, dispatch order, frontier,
//   shape, stream split). Residual above the 31 us pure-write model is
//   consistent with stores victimizing poison-dirtied L2/L3 lines
//   (~2x effective write traffic) - not kernel-addressable.
// Structure: block = (8 j) x (8 batch rows), bg-major dispatch; coef in
// 32 regs/lane; basis TRANSPOSED in LDS (conflict-free b128 reads); pure
// register dot; float4 stores (1KB contiguous per wave); batched 5-step
// y_out butterfly; phase-1 reciprocal-hoisted Cox-de Boor (verified).

#define IN_DIM  128
#define OUT_DIM 128
#define NUMG    5
#define KORD    3
#define NB      8          // NUMG + KORD basis functions
#define SIZE    (IN_DIM * OUT_DIM)
#define BATCH   1024
#define G       8          // batch rows per block
#define JB      8          // j per block
#define NBG     (BATCH / G)    // 128 batch groups
#define NJO     (OUT_DIM / JB) // 16 j groups

__global__ __launch_bounds__(256) void kan_fused(
    const float* __restrict__ x,
    const float* __restrict__ grid,
    const float* __restrict__ coef,
    const float* __restrict__ scale_base,
    const float* __restrict__ scale_sp,
    const float* __restrict__ mask,
    float* __restrict__ out)
{
    __shared__ float sBT[G][NB][IN_DIM];      // 32 KB [row][m][i] transposed
    __shared__ float sSilu[G][IN_DIM];        // 4 KB
    __shared__ float sXv[G][IN_DIM];          // 4 KB

    const int tid = threadIdx.x;
    const int bg  = blockIdx.x >> 4;          // batch group: HIGH bits ->
    const int jo  = blockIdx.x & (NJO - 1);   //  co-resident blocks share a
                                              //  compact batch slab (bg-major)

    // ---- Phase-2 operand loads issued FIRST (independent of LDS/barrier;
    //      latency hides under phase-1 compute) ----
    const int lane = tid & 63;
    const int w    = tid >> 6;
    const int il   = lane & 31;                // i-quad index
    const int jh   = lane >> 5;                // which j of the wave's pair
    const int i4   = il << 2;
    const int j    = jo * JB + w * 2 + jh;

    // Coef for THIS lane's 4 i at THIS j: 8 float4 = 32 regs, loaded once.
    float4 cfq[8];
    {
        const float4* cp = (const float4*)coef;
        #pragma unroll
        for (int q = 0; q < 8; ++q)
            cfq[q] = cp[(size_t)j * 256 + il * 8 + q];
    }
    const int sS = j * IN_DIM + i4;
    const float4 mkv = *(const float4*)&mask[sS];
    const float4 sbv = *(const float4*)&scale_base[sS];
    const float4 ssv = *(const float4*)&scale_sp[sS];

    // ---- Phase 1: basis + silu, 4 rows per thread, all same i ----
    {
        const int i  = tid & 127;
        const int r0 = tid >> 7;              // 0 or 1

        float gr[NUMG + 1];
        #pragma unroll
        for (int rr = 0; rr <= NUMG; ++rr) gr[rr] = grid[i * (NUMG + 1) + rr];

        const float h = (gr[NUMG] - gr[0]) * (1.0f / NUMG);
        float t[NUMG + 1 + 2 * KORD];             // 12 knots
        t[2] = gr[0] - h; t[1] = t[2] - h; t[0] = t[1] - h;
        #pragma unroll
        for (int rr = 0; rr <= NUMG; ++rr) t[KORD + rr] = gr[rr];
        t[9] = gr[NUMG] + h; t[10] = t[9] + h; t[11] = t[10] + h;

        // knot-difference reciprocals (shared by all 4 rows of this thread)
        float rcp1[11], rcp2[10], rcp3[9];
        #pragma unroll
        for (int m = 0; m < 11; ++m) rcp1[m] = 1.0f / (t[m + 1] - t[m]);
        #pragma unroll
        for (int m = 0; m < 10; ++m) rcp2[m] = 1.0f / (t[m + 2] - t[m]);
        #pragma unroll
        for (int m = 0; m < 9;  ++m) rcp3[m] = 1.0f / (t[m + 3] - t[m]);

        #pragma unroll
        for (int it = 0; it < 4; ++it) {
            const int r = it * 2 + r0;
            const float xv = x[(bg * G + r) * IN_DIM + i];

            float B[NUMG + 2 * KORD];             // 11 -> 10 -> 9 -> 8
            #pragma unroll
            for (int m = 0; m < NUMG + 2 * KORD; ++m)
                B[m] = (xv >= t[m] && xv < t[m + 1]) ? 1.0f : 0.0f;
            #pragma unroll
            for (int m = 0; m < 10; ++m)
                B[m] = (xv - t[m]) * rcp1[m] * B[m]
                     + (t[m + 2] - xv) * rcp1[m + 1] * B[m + 1];
            #pragma unroll
            for (int m = 0; m < 9; ++m)
                B[m] = (xv - t[m]) * rcp2[m] * B[m]
                     + (t[m + 3] - xv) * rcp2[m + 1] * B[m + 1];
            #pragma unroll
            for (int m = 0; m < 8; ++m)
                B[m] = (xv - t[m]) * rcp3[m] * B[m]
                     + (t[m + 4] - xv) * rcp3[m + 1] * B[m + 1];

            #pragma unroll
            for (int m = 0; m < NB; ++m) sBT[r][m][i] = B[m];
            sSilu[r][i] = xv / (1.0f + __expf(-xv));
            sXv[r][i]   = xv;
        }
    }
    __syncthreads();

    // ---- Phase 2: pure register dot + streaming stores, no DS chains ----
    float cfs[4][NB];   // cfs[k][m] = coef[j][i4+k][m] (static indexing only)
    #pragma unroll
    for (int k = 0; k < 4; ++k) {
        const float4 lo = cfq[2 * k], hi = cfq[2 * k + 1];
        cfs[k][0] = lo.x; cfs[k][1] = lo.y; cfs[k][2] = lo.z; cfs[k][3] = lo.w;
        cfs[k][4] = hi.x; cfs[k][5] = hi.y; cfs[k][6] = hi.z; cfs[k][7] = hi.w;
    }
    const float mkA[4] = {mkv.x, mkv.y, mkv.z, mkv.w};
    const float sbA[4] = {sbv.x, sbv.y, sbv.z, sbv.w};
    const float ssA[4] = {ssv.x, ssv.y, ssv.z, ssv.w};

    float* out_y   = out;
    float* out_pre = out + BATCH * OUT_DIM;
    float* out_act = out_pre + (size_t)BATCH * SIZE;
    float* out_spl = out_act + (size_t)BATCH * SIZE;

    float py[G];                               // per-lane y_out partials (VGPR)

    #pragma unroll                             // FULL unroll: all static idx
    for (int r = 0; r < G; ++r) {
        // 8 independent b128 reads: basis[m] for this lane's 4 i
        float4 bas[NB];
        #pragma unroll
        for (int m = 0; m < NB; ++m)
            bas[m] = *(const float4*)&sBT[r][m][i4];

        float sp0 = cfs[0][0] * bas[0].x;
        float sp1 = cfs[1][0] * bas[0].y;
        float sp2 = cfs[2][0] * bas[0].z;
        float sp3 = cfs[3][0] * bas[0].w;
        #pragma unroll
        for (int m = 1; m < NB; ++m) {
            const float4 b4 = bas[m];
            sp0 = fmaf(cfs[0][m], b4.x, sp0);
            sp1 = fmaf(cfs[1][m], b4.y, sp1);
            sp2 = fmaf(cfs[2][m], b4.z, sp2);
            sp3 = fmaf(cfs[3][m], b4.w, sp3);
        }

        const float4 slv = *(const float4*)&sSilu[r][i4];
        const float4 pxv = *(const float4*)&sXv[r][i4];
        const float spA[4] = {sp0, sp1, sp2, sp3};
        const float slA[4] = {slv.x, slv.y, slv.z, slv.w};

        float y[4];
        #pragma unroll
        for (int k = 0; k < 4; ++k)
            y[k] = mkA[k] * (sbA[k] * slA[k] + ssA[k] * spA[k]);

        const int b_r = bg * G + r;
        const size_t e = (size_t)b_r * SIZE + (size_t)sS;
        *(float4*)&out_pre[e] = pxv;                            // x broadcast
        *(float4*)&out_act[e] = make_float4(y[0], y[1], y[2], y[3]);
        *(float4*)&out_spl[e] = make_float4(spA[0], spA[1], spA[2], spA[3]);

        py[r] = (y[0] + y[1]) + (y[2] + y[3]);
    }

    // ---- Batched y_out reduction: one butterfly for all 8 rows ----
    #pragma unroll
    for (int off = 16; off > 0; off >>= 1) {
        #pragma unroll
        for (int r = 0; r < G; ++r)
            py[r] += __shfl_down(py[r], off, 32);
    }
    if (il == 0) {
        #pragma unroll
        for (int r = 0; r < G; ++r)
            out_y[(bg * G + r) * OUT_DIM + j] = py[r];
    }
}

extern "C" void kernel_launch(void* const* d_in, const int* in_sizes, int n_in,
                              void* d_out, int out_size, void* d_ws, size_t ws_size,
                              hipStream_t stream)
{
    hipLaunchKernelGGL(kan_fused, dim3(NJO * NBG), dim3(256), 0, stream,
                       (const float*)d_in[0], (const float*)d_in[1],
                       (const float*)d_in[2], (const float*)d_in[3],
                       (const float*)d_in[4], (const float*)d_in[5],
                       (float*)d_out);
}